// Round 4
// baseline (258.674 us; speedup 1.0000x reference)
//
#include <hip/hip_runtime.h>
#include <math.h>

#define NVOX 50000
#define PPTS 32
#define HDIM 64
#define ODIM 128
#define EPSBN 1e-5f

// f16 row stride for activation tiles: 72 f16 = 144 B (conflict-free b128 reads,
// 2-way b64 writes -- free per m136).
#define RS 72

#define NCHUNK 25000           // 64-point chunks (2 voxels each)
#define NWAVE  5000            // persistent waves: exactly 5 chunks per wave
#define NBLK   1250

typedef _Float16 f16x8 __attribute__((ext_vector_type(8)));
typedef _Float16 f16x4 __attribute__((ext_vector_type(4)));
typedef float f32x4 __attribute__((ext_vector_type(4)));

// d_ws layout (f16 elements unless noted):
//   [0, 512)       W1c: 64 rows x 8 f16  {w0..w3, c1, 0,0,0}   (BN-folded layer1)
//   [512, 4608)    W2T: [ch_out][ch_in] 64x64, BN-folded
//   [4608, 12800)  W3T: [o][ch_in] 128x64
//   byte 25600:    f32 c2[64], f32 b3[128]
#define WS_W1C 0
#define WS_W2T 512
#define WS_W3T 4608
#define WS_F32_BYTE 25600
#define FOLD_THREADS 12992

__global__ void vfe_fold(
    const float* __restrict__ W1, const float* __restrict__ b1,
    const float* __restrict__ g1, const float* __restrict__ be1,
    const float* __restrict__ m1, const float* __restrict__ v1,
    const float* __restrict__ W2, const float* __restrict__ b2,
    const float* __restrict__ g2, const float* __restrict__ be2,
    const float* __restrict__ m2, const float* __restrict__ v2,
    const float* __restrict__ W3, const float* __restrict__ b3,
    _Float16* __restrict__ wsh, float* __restrict__ wsf)
{
    int t = blockIdx.x * 256 + threadIdx.x;
    if (t < 512) {                               // W1c
        int row = t >> 3, i = t & 7;
        float s1 = g1[row] * rsqrtf(v1[row] + EPSBN);
        float val;
        if (i < 4)      val = W1[i * 64 + row] * s1;
        else if (i == 4) val = (b1[row] - m1[row]) * s1 + be1[row];
        else             val = 0.f;
        wsh[WS_W1C + t] = (_Float16)val;
    } else if (t < 4608) {                       // W2T folded: [ch'][ch]
        int e = t - 512;
        int chp = e >> 6, ch = e & 63;
        float s2 = g2[chp] * rsqrtf(v2[chp] + EPSBN);
        wsh[t] = (_Float16)(W2[ch * 64 + chp] * s2);
    } else if (t < 12800) {                      // W3T: [o][ch]
        int e = t - 4608;
        int o = e >> 6, ch = e & 63;
        wsh[t] = (_Float16)W3[ch * 128 + o];
    } else if (t < 12864) {                      // c2
        int i = t - 12800;
        float s2 = g2[i] * rsqrtf(v2[i] + EPSBN);
        wsf[i] = (b2[i] - m2[i]) * s2 + be2[i];
    } else if (t < FOLD_THREADS) {               // b3
        int i = t - 12864;
        wsf[64 + i] = b3[i];
    }
}

__global__ __launch_bounds__(256, 2) void vfe_mfma(
    const float* __restrict__ vf, const int* __restrict__ vnp,
    const _Float16* __restrict__ wsh, const float* __restrict__ wsf,
    float* __restrict__ out)
{
    // per-wave, per-group activation tiles (h1/h2 share a tile within a group;
    // distinct tiles ACROSS groups let the compiler pipeline the 4 groups)
    __shared__ __align__(16) _Float16 sH[4][4][16 * RS];   // 36864 B

    const int tid  = threadIdx.x;
    const int wave = tid >> 6;
    const int lane = tid & 63;
    const int q    = lane >> 4;
    const int m16  = lane & 15;
    const int gwave = blockIdx.x * 4 + wave;     // 0..4999

    // ---- one-time per-wave register preloads from global (L2-resident) ----
    f16x8 a1[4];
#pragma unroll
    for (int mt = 0; mt < 4; ++mt) {
        f16x8 t = *(const f16x8*)&wsh[WS_W1C + (m16 + 16 * mt) * 8];
        a1[mt] = (q == 0) ? t : (f16x8)0;
    }
    f16x8 a2[4][2];
#pragma unroll
    for (int mt = 0; mt < 4; ++mt)
#pragma unroll
        for (int kk = 0; kk < 2; ++kk)
            a2[mt][kk] = *(const f16x8*)&wsh[WS_W2T + (m16 + 16 * mt) * 64 + kk * 32 + q * 8];
    f16x8 b3f[8][2];
#pragma unroll
    for (int nt = 0; nt < 8; ++nt)
#pragma unroll
        for (int kk = 0; kk < 2; ++kk)
            b3f[nt][kk] = *(const f16x8*)&wsh[WS_W3T + (m16 + 16 * nt) * 64 + kk * 32 + q * 8];
    f32x4 c2v[4];
#pragma unroll
    for (int mt = 0; mt < 4; ++mt)
        c2v[mt] = *(const f32x4*)(wsf + mt * 16 + q * 4);
    float b3r[8];
#pragma unroll
    for (int nt = 0; nt < 8; ++nt) b3r[nt] = wsf[64 + nt * 16 + m16];

    // ---- prime chunk 0 inputs ----
    int c = gwave;
    float4 xv[4];
#pragma unroll
    for (int g = 0; g < 4; ++g)
        xv[g] = *(const float4*)(vf + ((size_t)c * 64 + g * 16 + m16) * 4);
    int nA = vnp[c * 2], nB = vnp[c * 2 + 1];

    for (int it = 0; it < 5; ++it) {
        // ---- prefetch next chunk (wraps harmlessly on last iter) ----
        int cn = c + NWAVE; if (cn >= NCHUNK) cn -= NCHUNK;
        float4 xn[4];
#pragma unroll
        for (int g = 0; g < 4; ++g)
            xn[g] = *(const float4*)(vf + ((size_t)cn * 64 + g * 16 + m16) * 4);
        int nAn = vnp[cn * 2], nBn = vnp[cn * 2 + 1];

        float vmA[8], vmB[8];
#pragma unroll
        for (int nt = 0; nt < 8; ++nt) { vmA[nt] = -INFINITY; vmB[nt] = -INFINITY; }

#pragma unroll
        for (int g = 0; g < 4; ++g) {            // g = v*2 + p2
            _Float16* ht = &sH[wave][g][0];
            const float4 x = xv[g];
            f16x8 bfrag = (f16x8)0;
            if (q == 0) {
                bfrag[0] = (_Float16)x.x; bfrag[1] = (_Float16)x.y;
                bfrag[2] = (_Float16)x.z; bfrag[3] = (_Float16)x.w;
                bfrag[4] = (_Float16)1.0f;       // homogeneous slot carries c1
            }

            // ---- layer 1 (transposed): D1[ch'][pt16] ----
#pragma unroll
            for (int mt = 0; mt < 4; ++mt) {
                f32x4 acc = {0.f, 0.f, 0.f, 0.f};
                acc = __builtin_amdgcn_mfma_f32_16x16x32_f16(a1[mt], bfrag, acc, 0, 0, 0);
                f16x4 h;
                h[0] = (_Float16)fmaxf(acc[0], 0.f);
                h[1] = (_Float16)fmaxf(acc[1], 0.f);
                h[2] = (_Float16)fmaxf(acc[2], 0.f);
                h[3] = (_Float16)fmaxf(acc[3], 0.f);
                *(f16x4*)&ht[m16 * RS + mt * 16 + q * 4] = h;
            }
            f16x8 b2f[2];
#pragma unroll
            for (int kk = 0; kk < 2; ++kk)
                b2f[kk] = *(const f16x8*)&ht[m16 * RS + kk * 32 + q * 8];

            // ---- layer 2 (transposed), bias via C operand ----
#pragma unroll
            for (int mt = 0; mt < 4; ++mt) {
                f32x4 acc = c2v[mt];
                acc = __builtin_amdgcn_mfma_f32_16x16x32_f16(a2[mt][0], b2f[0], acc, 0, 0, 0);
                acc = __builtin_amdgcn_mfma_f32_16x16x32_f16(a2[mt][1], b2f[1], acc, 0, 0, 0);
                f16x4 h;
                h[0] = (_Float16)fmaxf(acc[0], 0.f);
                h[1] = (_Float16)fmaxf(acc[1], 0.f);
                h[2] = (_Float16)fmaxf(acc[2], 0.f);
                h[3] = (_Float16)fmaxf(acc[3], 0.f);
                *(f16x4*)&ht[m16 * RS + mt * 16 + q * 4] = h;   // reuse tile
            }
            f16x8 a3[2];
#pragma unroll
            for (int kk = 0; kk < 2; ++kk)
                a3[kk] = *(const f16x8*)&ht[m16 * RS + kk * 32 + q * 8];

            // ---- layer 3 (normal), -inf validity mask via C operand ----
            const int n = (g < 2) ? nA : nB;
            const int slotbase = (g & 1) * 16 + q * 4;
            f32x4 macc;
#pragma unroll
            for (int r = 0; r < 4; ++r)
                macc[r] = (slotbase + r < n) ? 0.f : -INFINITY;
            float* vm = (g < 2) ? vmA : vmB;

#pragma unroll
            for (int nt = 0; nt < 8; ++nt) {
                f32x4 acc = macc;
                acc = __builtin_amdgcn_mfma_f32_16x16x32_f16(a3[0], b3f[nt][0], acc, 0, 0, 0);
                acc = __builtin_amdgcn_mfma_f32_16x16x32_f16(a3[1], b3f[nt][1], acc, 0, 0, 0);
                float m0 = fmaxf(fmaxf(acc[0], acc[1]), fmaxf(acc[2], acc[3]));
                vm[nt] = fmaxf(vm[nt], m0);
            }
        }

        // ---- epilogue: cross-quad max, bias, store (2 voxels) ----
#pragma unroll
        for (int nt = 0; nt < 8; ++nt) {
            float t0 = vmA[nt];
            t0 = fmaxf(t0, __shfl_xor(t0, 16));
            t0 = fmaxf(t0, __shfl_xor(t0, 32));
            float t1 = vmB[nt];
            t1 = fmaxf(t1, __shfl_xor(t1, 16));
            t1 = fmaxf(t1, __shfl_xor(t1, 32));
            if (q == 0) out[(size_t)(2 * c + 0) * ODIM + nt * 16 + m16] = t0 + b3r[nt];
            if (q == 1) out[(size_t)(2 * c + 1) * ODIM + nt * 16 + m16] = t1 + b3r[nt];
        }

        // ---- roll prefetched inputs ----
#pragma unroll
        for (int g = 0; g < 4; ++g) xv[g] = xn[g];
        nA = nAn; nB = nBn;
        c = cn;
    }
}

extern "C" void kernel_launch(void* const* d_in, const int* in_sizes, int n_in,
                              void* d_out, int out_size, void* d_ws, size_t ws_size,
                              hipStream_t stream) {
    const float* vf  = (const float*)d_in[0];
    const int*   vnp = (const int*)d_in[1];
    const float* W1  = (const float*)d_in[2];
    const float* b1  = (const float*)d_in[3];
    const float* g1  = (const float*)d_in[4];
    const float* be1 = (const float*)d_in[5];
    const float* m1  = (const float*)d_in[6];
    const float* v1  = (const float*)d_in[7];
    const float* W2  = (const float*)d_in[8];
    const float* b2  = (const float*)d_in[9];
    const float* g2  = (const float*)d_in[10];
    const float* be2 = (const float*)d_in[11];
    const float* m2  = (const float*)d_in[12];
    const float* v2  = (const float*)d_in[13];
    const float* W3  = (const float*)d_in[14];
    const float* b3  = (const float*)d_in[15];
    float* out = (float*)d_out;

    _Float16* wsh = (_Float16*)d_ws;
    float*    wsf = (float*)((char*)d_ws + WS_F32_BYTE);

    vfe_fold<<<(FOLD_THREADS + 255) / 256, 256, 0, stream>>>(
        W1, b1, g1, be1, m1, v1, W2, b2, g2, be2, m2, v2, W3, b3, wsh, wsf);

    vfe_mfma<<<NBLK, 256, 0, stream>>>(vf, vnp, wsh, wsf, out);
}

// Round 5
// 214.091 us; speedup vs baseline: 1.2082x; 1.2082x over previous
//
#include <hip/hip_runtime.h>
#include <math.h>

#define NVOX 50000
#define PPTS 32
#define HDIM 64
#define ODIM 128
#define EPSBN 1e-5f

// f16 row stride for activation tiles: 72 f16 = 144 B (conflict-free b128 reads,
// 2-way b64 writes -- free per m136).
#define RS 72

typedef _Float16 f16x8 __attribute__((ext_vector_type(8)));
typedef _Float16 f16x4 __attribute__((ext_vector_type(4)));
typedef float f32x4 __attribute__((ext_vector_type(4)));

// d_ws layout (f16 elements unless noted):
//   [0, 512)       W1c: 64 rows x 8 f16  {w0..w3, c1, 0,0,0}   (BN-folded layer1)
//   [512, 4608)    W2T: [ch_out][ch_in] 64x64, BN-folded
//   [4608, 12800)  W3T: [o][ch_in] 128x64
//   byte 25600:    f32 c2[64], f32 b3[128]
#define WS_W1C 0
#define WS_W2T 512
#define WS_W3T 4608
#define WS_F32_BYTE 25600
#define FOLD_THREADS 12992

__global__ void vfe_fold(
    const float* __restrict__ W1, const float* __restrict__ b1,
    const float* __restrict__ g1, const float* __restrict__ be1,
    const float* __restrict__ m1, const float* __restrict__ v1,
    const float* __restrict__ W2, const float* __restrict__ b2,
    const float* __restrict__ g2, const float* __restrict__ be2,
    const float* __restrict__ m2, const float* __restrict__ v2,
    const float* __restrict__ W3, const float* __restrict__ b3,
    _Float16* __restrict__ wsh, float* __restrict__ wsf)
{
    int t = blockIdx.x * 256 + threadIdx.x;
    if (t < 512) {                               // W1c
        int row = t >> 3, i = t & 7;
        float s1 = g1[row] * rsqrtf(v1[row] + EPSBN);
        float val;
        if (i < 4)      val = W1[i * 64 + row] * s1;
        else if (i == 4) val = (b1[row] - m1[row]) * s1 + be1[row];
        else             val = 0.f;
        wsh[WS_W1C + t] = (_Float16)val;
    } else if (t < 4608) {                       // W2T folded: [ch'][ch]
        int e = t - 512;
        int chp = e >> 6, ch = e & 63;
        float s2 = g2[chp] * rsqrtf(v2[chp] + EPSBN);
        wsh[t] = (_Float16)(W2[ch * 64 + chp] * s2);
    } else if (t < 12800) {                      // W3T: [o][ch]
        int e = t - 4608;
        int o = e >> 6, ch = e & 63;
        wsh[t] = (_Float16)W3[ch * 128 + o];
    } else if (t < 12864) {                      // c2
        int i = t - 12800;
        float s2 = g2[i] * rsqrtf(v2[i] + EPSBN);
        wsf[i] = (b2[i] - m2[i]) * s2 + be2[i];
    } else if (t < FOLD_THREADS) {               // b3
        int i = t - 12864;
        wsf[64 + i] = b3[i];
    }
}

__global__ __launch_bounds__(256, 2) void vfe_mfma(
    const float* __restrict__ vf, const int* __restrict__ vnp,
    const _Float16* __restrict__ wsh, const float* __restrict__ wsf,
    float* __restrict__ out)
{
    // Activation tiles, double-buffered by group parity (buf = p2):
    // adjacent point-groups use disjoint tiles -> no false LDS aliasing,
    // but liveness depth is bounded at 2 (round 4's 4-deep version spilled).
    __shared__ __align__(16) _Float16 sH[4][2][2][16 * RS];   // [wave][buf][h1/h2]

    const int tid  = threadIdx.x;
    const int wave = tid >> 6;
    const int lane = tid & 63;
    const int q    = lane >> 4;
    const int m16  = lane & 15;

    const int wavebase = blockIdx.x * 256 + wave * 64;  // 64 points = 2 voxels
    const int voxA = wavebase >> 5;

    // ---- register preloads straight from global (L2-resident) ----
    f16x8 a1[4];
#pragma unroll
    for (int mt = 0; mt < 4; ++mt) {
        f16x8 t = *(const f16x8*)&wsh[WS_W1C + (m16 + 16 * mt) * 8];
        a1[mt] = (q == 0) ? t : (f16x8)0;      // k = q*8+j; only k<8 carries data
    }
    f16x8 a2[4][2];
#pragma unroll
    for (int mt = 0; mt < 4; ++mt)
#pragma unroll
        for (int kk = 0; kk < 2; ++kk)
            a2[mt][kk] = *(const f16x8*)&wsh[WS_W2T + (m16 + 16 * mt) * 64 + kk * 32 + q * 8];
    f16x8 b3f[8][2];
#pragma unroll
    for (int nt = 0; nt < 8; ++nt)
#pragma unroll
        for (int kk = 0; kk < 2; ++kk)
            b3f[nt][kk] = *(const f16x8*)&wsh[WS_W3T + (m16 + 16 * nt) * 64 + kk * 32 + q * 8];
    f32x4 c2v[4];
#pragma unroll
    for (int mt = 0; mt < 4; ++mt)
        c2v[mt] = *(const f32x4*)(wsf + mt * 16 + q * 4);
    float b3r[8];
#pragma unroll
    for (int nt = 0; nt < 8; ++nt) b3r[nt] = wsf[64 + nt * 16 + m16];

    // ---- issue all point loads up front (latency paid once) ----
    float4 xv[4];
#pragma unroll
    for (int g = 0; g < 4; ++g)
        xv[g] = *(const float4*)(vf + ((size_t)wavebase + g * 16 + m16) * 4);
    const int nA = vnp[voxA];
    const int nB = vnp[voxA + 1];

#pragma unroll
    for (int v = 0; v < 2; ++v) {                // voxel voxA+v
        const int n = (v == 0) ? nA : nB;
        float vmax[8];
#pragma unroll
        for (int nt = 0; nt < 8; ++nt) vmax[nt] = -INFINITY;

#pragma unroll
        for (int p2 = 0; p2 < 2; ++p2) {         // 16-point half; buf = p2
            _Float16* h1t = &sH[wave][p2][0][0];
            _Float16* h2t = &sH[wave][p2][1][0];
            const float4 x = xv[v * 2 + p2];
            f16x8 bfrag = (f16x8)0;
            if (q == 0) {
                bfrag[0] = (_Float16)x.x; bfrag[1] = (_Float16)x.y;
                bfrag[2] = (_Float16)x.z; bfrag[3] = (_Float16)x.w;
                bfrag[4] = (_Float16)1.0f;       // homogeneous slot carries c1
            }

            // ---- layer 1 (transposed): D1[ch'][pt16] ----
#pragma unroll
            for (int mt = 0; mt < 4; ++mt) {
                f32x4 acc = {0.f, 0.f, 0.f, 0.f};
                acc = __builtin_amdgcn_mfma_f32_16x16x32_f16(a1[mt], bfrag, acc, 0, 0, 0);
                f16x4 h;
                h[0] = (_Float16)fmaxf(acc[0], 0.f);
                h[1] = (_Float16)fmaxf(acc[1], 0.f);
                h[2] = (_Float16)fmaxf(acc[2], 0.f);
                h[3] = (_Float16)fmaxf(acc[3], 0.f);
                *(f16x4*)&h1t[m16 * RS + mt * 16 + q * 4] = h;
            }
            f16x8 b2f[2];
#pragma unroll
            for (int kk = 0; kk < 2; ++kk)
                b2f[kk] = *(const f16x8*)&h1t[m16 * RS + kk * 32 + q * 8];

            // ---- layer 2 (transposed), bias via C operand ----
#pragma unroll
            for (int mt = 0; mt < 4; ++mt) {
                f32x4 acc = c2v[mt];
                acc = __builtin_amdgcn_mfma_f32_16x16x32_f16(a2[mt][0], b2f[0], acc, 0, 0, 0);
                acc = __builtin_amdgcn_mfma_f32_16x16x32_f16(a2[mt][1], b2f[1], acc, 0, 0, 0);
                f16x4 h;
                h[0] = (_Float16)fmaxf(acc[0], 0.f);
                h[1] = (_Float16)fmaxf(acc[1], 0.f);
                h[2] = (_Float16)fmaxf(acc[2], 0.f);
                h[3] = (_Float16)fmaxf(acc[3], 0.f);
                *(f16x4*)&h2t[m16 * RS + mt * 16 + q * 4] = h;
            }
            f16x8 a3[2];
#pragma unroll
            for (int kk = 0; kk < 2; ++kk)
                a3[kk] = *(const f16x8*)&h2t[m16 * RS + kk * 32 + q * 8];

            // ---- layer 3 (normal), -inf validity mask via C operand ----
            const int slotbase = p2 * 16 + q * 4;
            f32x4 macc;
#pragma unroll
            for (int r = 0; r < 4; ++r)
                macc[r] = (slotbase + r < n) ? 0.f : -INFINITY;

#pragma unroll
            for (int nt = 0; nt < 8; ++nt) {
                f32x4 acc = macc;
                acc = __builtin_amdgcn_mfma_f32_16x16x32_f16(a3[0], b3f[nt][0], acc, 0, 0, 0);
                acc = __builtin_amdgcn_mfma_f32_16x16x32_f16(a3[1], b3f[nt][1], acc, 0, 0, 0);
                float m0 = fmaxf(fmaxf(acc[0], acc[1]), fmaxf(acc[2], acc[3]));
                vmax[nt] = fmaxf(vmax[nt], m0);
            }
        }

        // ---- epilogue: cross-quad max, bias, store ----
#pragma unroll
        for (int nt = 0; nt < 8; ++nt) {
            float t = vmax[nt];
            t = fmaxf(t, __shfl_xor(t, 16));
            t = fmaxf(t, __shfl_xor(t, 32));
            if (q == v)
                out[(size_t)(voxA + v) * ODIM + nt * 16 + m16] = t + b3r[nt];
        }
    }
}

extern "C" void kernel_launch(void* const* d_in, const int* in_sizes, int n_in,
                              void* d_out, int out_size, void* d_ws, size_t ws_size,
                              hipStream_t stream) {
    const float* vf  = (const float*)d_in[0];
    const int*   vnp = (const int*)d_in[1];
    const float* W1  = (const float*)d_in[2];
    const float* b1  = (const float*)d_in[3];
    const float* g1  = (const float*)d_in[4];
    const float* be1 = (const float*)d_in[5];
    const float* m1  = (const float*)d_in[6];
    const float* v1  = (const float*)d_in[7];
    const float* W2  = (const float*)d_in[8];
    const float* b2  = (const float*)d_in[9];
    const float* g2  = (const float*)d_in[10];
    const float* be2 = (const float*)d_in[11];
    const float* m2  = (const float*)d_in[12];
    const float* v2  = (const float*)d_in[13];
    const float* W3  = (const float*)d_in[14];
    const float* b3  = (const float*)d_in[15];
    float* out = (float*)d_out;

    _Float16* wsh = (_Float16*)d_ws;
    float*    wsf = (float*)((char*)d_ws + WS_F32_BYTE);

    vfe_fold<<<(FOLD_THREADS + 255) / 256, 256, 0, stream>>>(
        W1, b1, g1, be1, m1, v1, W2, b2, g2, be2, m2, v2, W3, b3, wsh, wsf);

    const int blocks = (NVOX * PPTS) / 256;   // 6250
    vfe_mfma<<<blocks, 256, 0, stream>>>(vf, vnp, wsh, wsf, out);
}

// Round 6
// 189.372 us; speedup vs baseline: 1.3660x; 1.1305x over previous
//
#include <hip/hip_runtime.h>
#include <math.h>

#define NVOX 50000
#define PPTS 32
#define HDIM 64
#define ODIM 128
#define EPSBN 1e-5f

// f16 row stride for activation tiles: 72 f16 = 144 B (conflict-free b128 reads,
// 2-way b64 writes -- free per m136).
#define RS 72

typedef _Float16 f16x8 __attribute__((ext_vector_type(8)));
typedef _Float16 f16x4 __attribute__((ext_vector_type(4)));
typedef float f32x4 __attribute__((ext_vector_type(4)));

// d_ws layout (f16 elements unless noted):
//   [0, 512)       W1c: 64 rows x 8 f16  {w0..w3, c1, 0,0,0}   (BN-folded layer1)
//   [512, 4608)    W2T: [ch_out][ch_in] 64x64, BN-folded
//   [4608, 12800)  W3T: [o][ch_in] 128x64
//   byte 25600:    f32 c2[64], f32 b3[128]
#define WS_W1C 0
#define WS_W2T 512
#define WS_W3T 4608
#define WS_F32_BYTE 25600
#define FOLD_THREADS 12992

__global__ void vfe_fold(
    const float* __restrict__ W1, const float* __restrict__ b1,
    const float* __restrict__ g1, const float* __restrict__ be1,
    const float* __restrict__ m1, const float* __restrict__ v1,
    const float* __restrict__ W2, const float* __restrict__ b2,
    const float* __restrict__ g2, const float* __restrict__ be2,
    const float* __restrict__ m2, const float* __restrict__ v2,
    const float* __restrict__ W3, const float* __restrict__ b3,
    _Float16* __restrict__ wsh, float* __restrict__ wsf)
{
    int t = blockIdx.x * 256 + threadIdx.x;
    if (t < 512) {                               // W1c
        int row = t >> 3, i = t & 7;
        float s1 = g1[row] * rsqrtf(v1[row] + EPSBN);
        float val;
        if (i < 4)      val = W1[i * 64 + row] * s1;
        else if (i == 4) val = (b1[row] - m1[row]) * s1 + be1[row];
        else             val = 0.f;
        wsh[WS_W1C + t] = (_Float16)val;
    } else if (t < 4608) {                       // W2T folded: [ch'][ch]
        int e = t - 512;
        int chp = e >> 6, ch = e & 63;
        float s2 = g2[chp] * rsqrtf(v2[chp] + EPSBN);
        wsh[t] = (_Float16)(W2[ch * 64 + chp] * s2);
    } else if (t < 12800) {                      // W3T: [o][ch]
        int e = t - 4608;
        int o = e >> 6, ch = e & 63;
        wsh[t] = (_Float16)W3[ch * 128 + o];
    } else if (t < 12864) {                      // c2
        int i = t - 12800;
        float s2 = g2[i] * rsqrtf(v2[i] + EPSBN);
        wsf[i] = (b2[i] - m2[i]) * s2 + be2[i];
    } else if (t < FOLD_THREADS) {               // b3
        int i = t - 12864;
        wsf[64 + i] = b3[i];
    }
}

__global__ __launch_bounds__(256, 2) void vfe_mfma(
    const float* __restrict__ vf, const int* __restrict__ vnp,
    const _Float16* __restrict__ wsh, const float* __restrict__ wsf,
    float* __restrict__ out)
{
    // Per-wave tiles: [g] holds h1 of group g, [4+g] holds h2 of group g.
    // Phase-batched execution: all groups' writes are in flight before the
    // next phase's first read -> one lgkmcnt drain per LAYER, not per group.
    __shared__ __align__(16) _Float16 sH[4][8][16 * RS];   // 73728 B

    const int tid  = threadIdx.x;
    const int wave = tid >> 6;
    const int lane = tid & 63;
    const int q    = lane >> 4;
    const int m16  = lane & 15;

    const int wavebase = blockIdx.x * 256 + wave * 64;  // 64 points = 2 voxels
    const int voxA = wavebase >> 5;

    // ---- scalar-ish loads first (vnp index is wave-uniform) ----
    const int nA = vnp[voxA];
    const int nB = vnp[voxA + 1];

    // ---- register preloads straight from global (L1/L2-resident) ----
    f16x8 a1[4];
#pragma unroll
    for (int mt = 0; mt < 4; ++mt) {
        f16x8 t = *(const f16x8*)&wsh[WS_W1C + (m16 + 16 * mt) * 8];
        a1[mt] = (q == 0) ? t : (f16x8)0;      // k = q*8+j; only k<8 carries data
    }
    f16x8 a2[4][2];
#pragma unroll
    for (int mt = 0; mt < 4; ++mt)
#pragma unroll
        for (int kk = 0; kk < 2; ++kk)
            a2[mt][kk] = *(const f16x8*)&wsh[WS_W2T + (m16 + 16 * mt) * 64 + kk * 32 + q * 8];
    f16x8 b3f[8][2];
#pragma unroll
    for (int nt = 0; nt < 8; ++nt)
#pragma unroll
        for (int kk = 0; kk < 2; ++kk)
            b3f[nt][kk] = *(const f16x8*)&wsh[WS_W3T + (m16 + 16 * nt) * 64 + kk * 32 + q * 8];
    f32x4 c2v[4];
#pragma unroll
    for (int mt = 0; mt < 4; ++mt)
        c2v[mt] = *(const f32x4*)(wsf + mt * 16 + q * 4);
    float b3r[8];
#pragma unroll
    for (int nt = 0; nt < 8; ++nt) b3r[nt] = wsf[64 + nt * 16 + m16];

    // ---- point loads (all 4 groups up front) ----
    float4 xv[4];
#pragma unroll
    for (int g = 0; g < 4; ++g)
        xv[g] = *(const float4*)(vf + ((size_t)wavebase + g * 16 + m16) * 4);

    // ---- build all B1 fragments ----
    f16x8 bf[4];
#pragma unroll
    for (int g = 0; g < 4; ++g) {
        f16x8 b = (f16x8)0;
        if (q == 0) {
            b[0] = (_Float16)xv[g].x; b[1] = (_Float16)xv[g].y;
            b[2] = (_Float16)xv[g].z; b[3] = (_Float16)xv[g].w;
            b[4] = (_Float16)1.0f;               // homogeneous slot carries c1
        }
        bf[g] = b;
    }

    // ======== PHASE 1: layer 1 for all groups (transposed D1[ch'][pt16]) ========
#pragma unroll
    for (int g = 0; g < 4; ++g) {
        _Float16* h1t = &sH[wave][g][0];
#pragma unroll
        for (int mt = 0; mt < 4; ++mt) {
            f32x4 acc = {0.f, 0.f, 0.f, 0.f};
            acc = __builtin_amdgcn_mfma_f32_16x16x32_f16(a1[mt], bf[g], acc, 0, 0, 0);
            f16x4 h;
            h[0] = (_Float16)fmaxf(acc[0], 0.f);
            h[1] = (_Float16)fmaxf(acc[1], 0.f);
            h[2] = (_Float16)fmaxf(acc[2], 0.f);
            h[3] = (_Float16)fmaxf(acc[3], 0.f);
            *(f16x4*)&h1t[m16 * RS + mt * 16 + q * 4] = h;
        }
    }

    // ======== PHASE 2: layer 2 for all groups (bias via C operand) ========
#pragma unroll
    for (int g = 0; g < 4; ++g) {
        _Float16* h1t = &sH[wave][g][0];
        _Float16* h2t = &sH[wave][4 + g][0];
        f16x8 b2f0 = *(const f16x8*)&h1t[m16 * RS + q * 8];
        f16x8 b2f1 = *(const f16x8*)&h1t[m16 * RS + 32 + q * 8];
#pragma unroll
        for (int mt = 0; mt < 4; ++mt) {
            f32x4 acc = c2v[mt];
            acc = __builtin_amdgcn_mfma_f32_16x16x32_f16(a2[mt][0], b2f0, acc, 0, 0, 0);
            acc = __builtin_amdgcn_mfma_f32_16x16x32_f16(a2[mt][1], b2f1, acc, 0, 0, 0);
            f16x4 h;
            h[0] = (_Float16)fmaxf(acc[0], 0.f);
            h[1] = (_Float16)fmaxf(acc[1], 0.f);
            h[2] = (_Float16)fmaxf(acc[2], 0.f);
            h[3] = (_Float16)fmaxf(acc[3], 0.f);
            *(f16x4*)&h2t[m16 * RS + mt * 16 + q * 4] = h;
        }
    }

    // ======== PHASE 3: layer 3 for all groups, masked voxel max ========
    float vmA[8], vmB[8];
#pragma unroll
    for (int nt = 0; nt < 8; ++nt) { vmA[nt] = -INFINITY; vmB[nt] = -INFINITY; }

#pragma unroll
    for (int g = 0; g < 4; ++g) {                // g = v*2 + p2  (compile-time)
        _Float16* h2t = &sH[wave][4 + g][0];
        f16x8 a30 = *(const f16x8*)&h2t[m16 * RS + q * 8];
        f16x8 a31 = *(const f16x8*)&h2t[m16 * RS + 32 + q * 8];

        const int n = (g < 2) ? nA : nB;
        const int slotbase = (g & 1) * 16 + q * 4;
        f32x4 macc;
#pragma unroll
        for (int r = 0; r < 4; ++r)
            macc[r] = (slotbase + r < n) ? 0.f : -INFINITY;

#pragma unroll
        for (int nt = 0; nt < 8; ++nt) {
            f32x4 acc = macc;
            acc = __builtin_amdgcn_mfma_f32_16x16x32_f16(a30, b3f[nt][0], acc, 0, 0, 0);
            acc = __builtin_amdgcn_mfma_f32_16x16x32_f16(a31, b3f[nt][1], acc, 0, 0, 0);
            float m0 = fmaxf(fmaxf(acc[0], acc[1]), fmaxf(acc[2], acc[3]));
            if (g < 2) vmA[nt] = fmaxf(vmA[nt], m0);
            else       vmB[nt] = fmaxf(vmB[nt], m0);
        }
    }

    // ======== epilogue: cross-quad max, bias, store (2 voxels) ========
#pragma unroll
    for (int nt = 0; nt < 8; ++nt) {
        float t0 = vmA[nt];
        t0 = fmaxf(t0, __shfl_xor(t0, 16));
        t0 = fmaxf(t0, __shfl_xor(t0, 32));
        float t1 = vmB[nt];
        t1 = fmaxf(t1, __shfl_xor(t1, 16));
        t1 = fmaxf(t1, __shfl_xor(t1, 32));
        if (q == 0) out[(size_t)(voxA + 0) * ODIM + nt * 16 + m16] = t0 + b3r[nt];
        if (q == 1) out[(size_t)(voxA + 1) * ODIM + nt * 16 + m16] = t1 + b3r[nt];
    }
}

extern "C" void kernel_launch(void* const* d_in, const int* in_sizes, int n_in,
                              void* d_out, int out_size, void* d_ws, size_t ws_size,
                              hipStream_t stream) {
    const float* vf  = (const float*)d_in[0];
    const int*   vnp = (const int*)d_in[1];
    const float* W1  = (const float*)d_in[2];
    const float* b1  = (const float*)d_in[3];
    const float* g1  = (const float*)d_in[4];
    const float* be1 = (const float*)d_in[5];
    const float* m1  = (const float*)d_in[6];
    const float* v1  = (const float*)d_in[7];
    const float* W2  = (const float*)d_in[8];
    const float* b2  = (const float*)d_in[9];
    const float* g2  = (const float*)d_in[10];
    const float* be2 = (const float*)d_in[11];
    const float* m2  = (const float*)d_in[12];
    const float* v2  = (const float*)d_in[13];
    const float* W3  = (const float*)d_in[14];
    const float* b3  = (const float*)d_in[15];
    float* out = (float*)d_out;

    _Float16* wsh = (_Float16*)d_ws;
    float*    wsf = (float*)((char*)d_ws + WS_F32_BYTE);

    vfe_fold<<<(FOLD_THREADS + 255) / 256, 256, 0, stream>>>(
        W1, b1, g1, be1, m1, v1, W2, b2, g2, be2, m2, v2, W3, b3, wsh, wsf);

    const int blocks = (NVOX * PPTS) / 256;   // 6250
    vfe_mfma<<<blocks, 256, 0, stream>>>(vf, vnp, wsh, wsf, out);
}

// Round 7
// 162.903 us; speedup vs baseline: 1.5879x; 1.1625x over previous
//
#include <hip/hip_runtime.h>
#include <math.h>

#define NVOX 50000
#define PPTS 32
#define HDIM 64
#define ODIM 128
#define EPSBN 1e-5f

// f16 row stride for activation tiles: 72 f16 = 144 B (conflict-free b128 reads,
// 2-way b64 writes -- free per m136).
#define RS 72

typedef _Float16 f16x8 __attribute__((ext_vector_type(8)));
typedef _Float16 f16x4 __attribute__((ext_vector_type(4)));
typedef float f32x4 __attribute__((ext_vector_type(4)));

// d_ws layout (f16 elements unless noted):
//   [0, 512)       W1c: 64 rows x 8 f16  {w0..w3, c1, 0,0,0}   (BN-folded layer1)
//   [512, 4608)    W2T: [ch_out][ch_in] 64x64, BN-folded
//   [4608, 12800)  W3T: [o][ch_in] 128x64
//   byte 25600:    f32 c2[64], f32 b3[128]
#define WS_W1C 0
#define WS_W2T 512
#define WS_W3T 4608
#define WS_F32_BYTE 25600
#define FOLD_THREADS 12992

__global__ void vfe_fold(
    const float* __restrict__ W1, const float* __restrict__ b1,
    const float* __restrict__ g1, const float* __restrict__ be1,
    const float* __restrict__ m1, const float* __restrict__ v1,
    const float* __restrict__ W2, const float* __restrict__ b2,
    const float* __restrict__ g2, const float* __restrict__ be2,
    const float* __restrict__ m2, const float* __restrict__ v2,
    const float* __restrict__ W3, const float* __restrict__ b3,
    _Float16* __restrict__ wsh, float* __restrict__ wsf)
{
    int t = blockIdx.x * 256 + threadIdx.x;
    if (t < 512) {                               // W1c
        int row = t >> 3, i = t & 7;
        float s1 = g1[row] * rsqrtf(v1[row] + EPSBN);
        float val;
        if (i < 4)      val = W1[i * 64 + row] * s1;
        else if (i == 4) val = (b1[row] - m1[row]) * s1 + be1[row];
        else             val = 0.f;
        wsh[WS_W1C + t] = (_Float16)val;
    } else if (t < 4608) {                       // W2T folded: [ch'][ch]
        int e = t - 512;
        int chp = e >> 6, ch = e & 63;
        float s2 = g2[chp] * rsqrtf(v2[chp] + EPSBN);
        wsh[t] = (_Float16)(W2[ch * 64 + chp] * s2);
    } else if (t < 12800) {                      // W3T: [o][ch]
        int e = t - 4608;
        int o = e >> 6, ch = e & 63;
        wsh[t] = (_Float16)W3[ch * 128 + o];
    } else if (t < 12864) {                      // c2
        int i = t - 12800;
        float s2 = g2[i] * rsqrtf(v2[i] + EPSBN);
        wsf[i] = (b2[i] - m2[i]) * s2 + be2[i];
    } else if (t < FOLD_THREADS) {               // b3
        int i = t - 12864;
        wsf[64 + i] = b3[i];
    }
}

__global__ __launch_bounds__(256, 3) void vfe_mfma(
    const float* __restrict__ vf, const int* __restrict__ vnp,
    const _Float16* __restrict__ wsh, const float* __restrict__ wsf,
    float* __restrict__ out)
{
    // Per-wave activation tiles (in-place: h1 then h2 of group g share tile[g];
    // phase 2 reads tile[g] strictly before writing it -> per-wave DS order OK).
    __shared__ __align__(16) _Float16 sH[4][4][16 * RS];   // 36864 B
    // Block-shared W3 tile: [o][ch] stride 64, XOR-swizzled by 16B granule so
    // phase-3 reads (o = nt*16+m16 per lane) are conflict-free without padding.
    __shared__ __align__(16) _Float16 sW3[ODIM * HDIM];    // 16384 B
    // total LDS = 53248 B -> 3 blocks/CU; launch_bounds(256,3) caps regs at 170

    const int tid  = threadIdx.x;
    const int wave = tid >> 6;
    const int lane = tid & 63;
    const int q    = lane >> 4;
    const int m16  = lane & 15;

    const int wavebase = blockIdx.x * 256 + wave * 64;  // 64 points = 2 voxels
    const int voxA = wavebase >> 5;

    // ---- stage W3 into LDS (granule-swizzled), all 256 threads ----
#pragma unroll
    for (int i = 0; i < 4; ++i) {
        int G = tid + 256 * i;                   // granule id, 0..1023
        int o = G >> 3, gl = G & 7;              // row, logical 16B granule
        int ph = gl ^ (o & 7);                   // physical granule (XOR swizzle)
        f16x8 v = *(const f16x8*)&wsh[WS_W3T + o * 64 + gl * 8];
        *(f16x8*)&sW3[o * 64 + ph * 8] = v;
    }

    // ---- wave-uniform / per-lane global preloads ----
    const int nA = vnp[voxA];
    const int nB = vnp[voxA + 1];

    f16x8 a1[4];
#pragma unroll
    for (int mt = 0; mt < 4; ++mt) {
        f16x8 t = *(const f16x8*)&wsh[WS_W1C + (m16 + 16 * mt) * 8];
        a1[mt] = (q == 0) ? t : (f16x8)0;      // k = q*8+j; only k<8 carries data
    }
    f16x8 a2[4][2];
#pragma unroll
    for (int mt = 0; mt < 4; ++mt)
#pragma unroll
        for (int kk = 0; kk < 2; ++kk)
            a2[mt][kk] = *(const f16x8*)&wsh[WS_W2T + (m16 + 16 * mt) * 64 + kk * 32 + q * 8];
    f32x4 c2v[4];
#pragma unroll
    for (int mt = 0; mt < 4; ++mt)
        c2v[mt] = *(const f32x4*)(wsf + mt * 16 + q * 4);
    float b3r[8];
#pragma unroll
    for (int nt = 0; nt < 8; ++nt) b3r[nt] = wsf[64 + nt * 16 + m16];

    float4 xv[4];
#pragma unroll
    for (int g = 0; g < 4; ++g)
        xv[g] = *(const float4*)(vf + ((size_t)wavebase + g * 16 + m16) * 4);

    f16x8 bf[4];
#pragma unroll
    for (int g = 0; g < 4; ++g) {
        f16x8 b = (f16x8)0;
        if (q == 0) {
            b[0] = (_Float16)xv[g].x; b[1] = (_Float16)xv[g].y;
            b[2] = (_Float16)xv[g].z; b[3] = (_Float16)xv[g].w;
            b[4] = (_Float16)1.0f;               // homogeneous slot carries c1
        }
        bf[g] = b;
    }

    __syncthreads();                             // W3 tile ready (only barrier)

    // ======== PHASE 1: layer 1 for all groups (transposed D1[ch'][pt16]) ========
#pragma unroll
    for (int g = 0; g < 4; ++g) {
        _Float16* ht = &sH[wave][g][0];
#pragma unroll
        for (int mt = 0; mt < 4; ++mt) {
            f32x4 acc = {0.f, 0.f, 0.f, 0.f};
            acc = __builtin_amdgcn_mfma_f32_16x16x32_f16(a1[mt], bf[g], acc, 0, 0, 0);
            f16x4 h;
            h[0] = (_Float16)fmaxf(acc[0], 0.f);
            h[1] = (_Float16)fmaxf(acc[1], 0.f);
            h[2] = (_Float16)fmaxf(acc[2], 0.f);
            h[3] = (_Float16)fmaxf(acc[3], 0.f);
            *(f16x4*)&ht[m16 * RS + mt * 16 + q * 4] = h;
        }
    }

    // ======== PHASE 2: layer 2 for all groups (in-place h2 over h1) ========
    f16x8 b2f[4][2];
#pragma unroll
    for (int g = 0; g < 4; ++g) {
        _Float16* ht = &sH[wave][g][0];
        b2f[g][0] = *(const f16x8*)&ht[m16 * RS + q * 8];
        b2f[g][1] = *(const f16x8*)&ht[m16 * RS + 32 + q * 8];
    }
#pragma unroll
    for (int g = 0; g < 4; ++g) {
        _Float16* ht = &sH[wave][g][0];
#pragma unroll
        for (int mt = 0; mt < 4; ++mt) {
            f32x4 acc = c2v[mt];
            acc = __builtin_amdgcn_mfma_f32_16x16x32_f16(a2[mt][0], b2f[g][0], acc, 0, 0, 0);
            acc = __builtin_amdgcn_mfma_f32_16x16x32_f16(a2[mt][1], b2f[g][1], acc, 0, 0, 0);
            f16x4 h;
            h[0] = (_Float16)fmaxf(acc[0], 0.f);
            h[1] = (_Float16)fmaxf(acc[1], 0.f);
            h[2] = (_Float16)fmaxf(acc[2], 0.f);
            h[3] = (_Float16)fmaxf(acc[3], 0.f);
            *(f16x4*)&ht[m16 * RS + mt * 16 + q * 4] = h;
        }
    }

    // ======== PHASE 3: layer 3, nt-outer / g-inner, W3 frags from LDS ========
    f16x8 a3[4][2];
#pragma unroll
    for (int g = 0; g < 4; ++g) {
        _Float16* ht = &sH[wave][g][0];
        a3[g][0] = *(const f16x8*)&ht[m16 * RS + q * 8];
        a3[g][1] = *(const f16x8*)&ht[m16 * RS + 32 + q * 8];
    }

    f32x4 macc4[4];
#pragma unroll
    for (int g = 0; g < 4; ++g) {
        const int n = (g < 2) ? nA : nB;
        const int slotbase = (g & 1) * 16 + q * 4;
#pragma unroll
        for (int r = 0; r < 4; ++r)
            macc4[g][r] = (slotbase + r < n) ? 0.f : -INFINITY;
    }

    float vmA[8], vmB[8];
#pragma unroll
    for (int nt = 0; nt < 8; ++nt) { vmA[nt] = -INFINITY; vmB[nt] = -INFINITY; }

#pragma unroll
    for (int nt = 0; nt < 8; ++nt) {
        const int o = nt * 16 + m16;
        f16x8 b30 = *(const f16x8*)&sW3[o * 64 + ((q    ) ^ (m16 & 7)) * 8];
        f16x8 b31 = *(const f16x8*)&sW3[o * 64 + ((4 + q) ^ (m16 & 7)) * 8];
#pragma unroll
        for (int g = 0; g < 4; ++g) {
            f32x4 acc = macc4[g];
            acc = __builtin_amdgcn_mfma_f32_16x16x32_f16(a3[g][0], b30, acc, 0, 0, 0);
            acc = __builtin_amdgcn_mfma_f32_16x16x32_f16(a3[g][1], b31, acc, 0, 0, 0);
            float m0 = fmaxf(fmaxf(acc[0], acc[1]), fmaxf(acc[2], acc[3]));
            if (g < 2) vmA[nt] = fmaxf(vmA[nt], m0);
            else       vmB[nt] = fmaxf(vmB[nt], m0);
        }
    }

    // ======== epilogue: cross-quad max, bias, store (2 voxels) ========
#pragma unroll
    for (int nt = 0; nt < 8; ++nt) {
        float t0 = vmA[nt];
        t0 = fmaxf(t0, __shfl_xor(t0, 16));
        t0 = fmaxf(t0, __shfl_xor(t0, 32));
        float t1 = vmB[nt];
        t1 = fmaxf(t1, __shfl_xor(t1, 16));
        t1 = fmaxf(t1, __shfl_xor(t1, 32));
        if (q == 0) out[(size_t)(voxA + 0) * ODIM + nt * 16 + m16] = t0 + b3r[nt];
        if (q == 1) out[(size_t)(voxA + 1) * ODIM + nt * 16 + m16] = t1 + b3r[nt];
    }
}

extern "C" void kernel_launch(void* const* d_in, const int* in_sizes, int n_in,
                              void* d_out, int out_size, void* d_ws, size_t ws_size,
                              hipStream_t stream) {
    const float* vf  = (const float*)d_in[0];
    const int*   vnp = (const int*)d_in[1];
    const float* W1  = (const float*)d_in[2];
    const float* b1  = (const float*)d_in[3];
    const float* g1  = (const float*)d_in[4];
    const float* be1 = (const float*)d_in[5];
    const float* m1  = (const float*)d_in[6];
    const float* v1  = (const float*)d_in[7];
    const float* W2  = (const float*)d_in[8];
    const float* b2  = (const float*)d_in[9];
    const float* g2  = (const float*)d_in[10];
    const float* be2 = (const float*)d_in[11];
    const float* m2  = (const float*)d_in[12];
    const float* v2  = (const float*)d_in[13];
    const float* W3  = (const float*)d_in[14];
    const float* b3  = (const float*)d_in[15];
    float* out = (float*)d_out;

    _Float16* wsh = (_Float16*)d_ws;
    float*    wsf = (float*)((char*)d_ws + WS_F32_BYTE);

    vfe_fold<<<(FOLD_THREADS + 255) / 256, 256, 0, stream>>>(
        W1, b1, g1, be1, m1, v1, W2, b2, g2, be2, m2, v2, W3, b3, wsh, wsf);

    const int blocks = (NVOX * PPTS) / 256;   // 6250
    vfe_mfma<<<blocks, 256, 0, stream>>>(vf, vnp, wsh, wsf, out);
}